// Round 1
// baseline (586.994 us; speedup 1.0000x reference)
//
#include <hip/hip_runtime.h>
#include <math.h>

#define NUM_LEVELS 16
#define LEVEL_DIM 2
#define LOG2_T 21
#define TABLE_SIZE (1u << LOG2_T)
#define HASH_MASK (TABLE_SIZE - 1u)
#define N_POINTS 262144

struct ResArgs { float r[NUM_LEVELS]; };

__global__ __launch_bounds__(256) void hash_embed_kernel(
    const float* __restrict__ x,
    const float* __restrict__ tables,
    float* __restrict__ out,
    ResArgs res)
{
    const int t = blockIdx.x * blockDim.x + threadIdx.x;
    const int n = t >> 4;       // point index
    const int l = t & 15;       // level index (fastest within wave -> coalesced out)
    if (n >= N_POINTS) return;

    // ---- replicate reference f32 arithmetic exactly ----
    const float px = x[n * 3 + 0];
    const float py = x[n * 3 + 1];
    const float pz = x[n * 3 + 2];
    const float nx = fminf(fmaxf((px + 2.0f) * 0.25f, 0.0f), 1.0f);
    const float ny = fminf(fmaxf((py + 2.0f) * 0.25f, 0.0f), 1.0f);
    const float nz = fminf(fmaxf((pz + 2.0f) * 0.25f, 0.0f), 1.0f);

    const float r = res.r[l];
    const float sx = nx * r;
    const float sy = ny * r;
    const float sz = nz * r;
    const float fx = floorf(sx), fy = floorf(sy), fz = floorf(sz);
    const float wx = sx - fx, wy = sy - fy, wz = sz - fz;
    const int ix = (int)fx, iy = (int)fy, iz = (int)fz;

    // spatial hash, wrapping uint32 (low 21 bits match int64 path)
    const uint32_t hx0 = (uint32_t)ix * 73856093u;
    const uint32_t hy0 = (uint32_t)iy * 19349663u;
    const uint32_t hz0 = (uint32_t)iz * 83492791u;
    const uint32_t hx1 = hx0 + 73856093u;
    const uint32_t hy1 = hy0 + 19349663u;
    const uint32_t hz1 = hz0 + 83492791u;

    const float ax = 1.0f - wx, ay = 1.0f - wy, az = 1.0f - wz;

    const float* __restrict__ tab = tables + (size_t)l * ((size_t)TABLE_SIZE * LEVEL_DIM);

    float f0 = 0.0f, f1 = 0.0f;
    #pragma unroll
    for (int c = 0; c < 8; ++c) {
        // OFFSETS order: c bit2 = x-offset, bit1 = y-offset, bit0 = z-offset
        const uint32_t hh = ((c & 4) ? hx1 : hx0) ^ ((c & 2) ? hy1 : hy0) ^ ((c & 1) ? hz1 : hz0);
        const uint32_t idx = hh & HASH_MASK;
        const float2 emb = *reinterpret_cast<const float2*>(tab + (size_t)idx * LEVEL_DIM);
        const float w = (((c & 4) ? wx : ax) * ((c & 2) ? wy : ay)) * ((c & 1) ? wz : az);
        f0 = fmaf(w, emb.x, f0);
        f1 = fmaf(w, emb.y, f1);
    }

    // out[n][l][d], level-major within point; consecutive lanes -> consecutive float2
    float2* o = reinterpret_cast<float2*>(out + (size_t)n * (NUM_LEVELS * LEVEL_DIM) + l * LEVEL_DIM);
    *o = make_float2(f0, f1);
}

extern "C" void kernel_launch(void* const* d_in, const int* in_sizes, int n_in,
                              void* d_out, int out_size, void* d_ws, size_t ws_size,
                              hipStream_t stream) {
    const float* x      = (const float*)d_in[0];
    const float* tables = (const float*)d_in[1];
    float* out          = (float*)d_out;

    // Replicate: _b = np.exp((np.log(2048) - np.log(16)) / 15); res_i = int(floor(16 * _b**i))
    // Done in double with libm on the host, matching the numpy scalar path.
    ResArgs ra;
    const double b = exp((log(2048.0) - log(16.0)) / 15.0);
    for (int i = 0; i < NUM_LEVELS; ++i) {
        ra.r[i] = (float)floor(16.0 * pow(b, (double)i));
    }

    const int total = N_POINTS * NUM_LEVELS;
    const int block = 256;
    const int grid = (total + block - 1) / block;
    hipLaunchKernelGGL(hash_embed_kernel, dim3(grid), dim3(block), 0, stream,
                       x, tables, out, ra);
}

// Round 2
// 387.507 us; speedup vs baseline: 1.5148x; 1.5148x over previous
//
#include <hip/hip_runtime.h>
#include <math.h>

#define NUM_LEVELS 16
#define LEVEL_DIM 2
#define LOG2_T 21
#define TABLE_SIZE (1u << LOG2_T)
#define HASH_MASK (TABLE_SIZE - 1u)
#define N_POINTS 262144
#define BLOCKS_PER_LEVEL (N_POINTS / 256)   // 1024

struct ResArgs { float r[NUM_LEVELS]; };

// ---- shared per-point math -------------------------------------------------
__device__ __forceinline__ void hash_point_level(
    const float* __restrict__ x, const float* __restrict__ tables,
    int n, int l, float r, float& f0, float& f1)
{
    const float px = x[n * 3 + 0];
    const float py = x[n * 3 + 1];
    const float pz = x[n * 3 + 2];
    const float nx = fminf(fmaxf((px + 2.0f) * 0.25f, 0.0f), 1.0f);
    const float ny = fminf(fmaxf((py + 2.0f) * 0.25f, 0.0f), 1.0f);
    const float nz = fminf(fmaxf((pz + 2.0f) * 0.25f, 0.0f), 1.0f);

    const float sx = nx * r, sy = ny * r, sz = nz * r;
    const float fx = floorf(sx), fy = floorf(sy), fz = floorf(sz);
    const float wx = sx - fx, wy = sy - fy, wz = sz - fz;
    const int ix = (int)fx, iy = (int)fy, iz = (int)fz;

    const uint32_t hx0 = (uint32_t)ix * 73856093u;
    const uint32_t hy0 = (uint32_t)iy * 19349663u;
    const uint32_t hz0 = (uint32_t)iz * 83492791u;
    const uint32_t hx1 = hx0 + 73856093u;
    const uint32_t hy1 = hy0 + 19349663u;
    const uint32_t hz1 = hz0 + 83492791u;

    const float ax = 1.0f - wx, ay = 1.0f - wy, az = 1.0f - wz;
    const float* __restrict__ tab = tables + (size_t)l * ((size_t)TABLE_SIZE * LEVEL_DIM);

    f0 = 0.0f; f1 = 0.0f;
    #pragma unroll
    for (int c = 0; c < 8; ++c) {
        const uint32_t hh = ((c & 4) ? hx1 : hx0) ^ ((c & 2) ? hy1 : hy0) ^ ((c & 1) ? hz1 : hz0);
        const uint32_t idx = hh & HASH_MASK;
        const float2 emb = *reinterpret_cast<const float2*>(tab + (size_t)idx * LEVEL_DIM);
        const float w = (((c & 4) ? wx : ax) * ((c & 2) ? wy : ay)) * ((c & 1) ? wz : az);
        f0 = fmaf(w, emb.x, f0);
        f1 = fmaf(w, emb.y, f1);
    }
}

// ---- phase 1: level-major gather, coalesced write to ws[l][n] --------------
__global__ __launch_bounds__(256) void hash_embed_phase1(
    const float* __restrict__ x,
    const float* __restrict__ tables,
    float2* __restrict__ ws,      // [NUM_LEVELS][N_POINTS]
    ResArgs res)
{
    const int bid = blockIdx.x;
    const int l = bid >> 10;                       // level = slow dispatch dim
    const int n = ((bid & (BLOCKS_PER_LEVEL - 1)) << 8) + threadIdx.x;
    float f0, f1;
    hash_point_level(x, tables, n, l, res.r[l], f0, f1);
    ws[(size_t)l * N_POINTS + n] = make_float2(f0, f1);
}

// ---- phase 2: transpose ws[l][n] -> out[n][l] ------------------------------
__global__ __launch_bounds__(256) void hash_embed_phase2(
    const float2* __restrict__ ws,
    float2* __restrict__ out)     // out[n][l] as float2
{
    __shared__ float2 tile[64][NUM_LEVELS + 1];
    const int n0 = blockIdx.x * 64;
    const int t = threadIdx.x;
    #pragma unroll
    for (int k = 0; k < 4; ++k) {
        const int e = k * 256 + t;
        const int l = e >> 6;          // 0..15
        const int j = e & 63;          // point within tile
        tile[j][l] = ws[(size_t)l * N_POINTS + n0 + j];
    }
    __syncthreads();
    #pragma unroll
    for (int k = 0; k < 4; ++k) {
        const int e = k * 256 + t;
        const int nl = e >> 4;         // 0..63
        const int l = e & 15;
        out[(size_t)(n0 + nl) * NUM_LEVELS + l] = tile[nl][l];
    }
}

// ---- fallback (R1-proven): interleaved levels, direct out ------------------
__global__ __launch_bounds__(256) void hash_embed_direct(
    const float* __restrict__ x,
    const float* __restrict__ tables,
    float* __restrict__ out,
    ResArgs res)
{
    const int t = blockIdx.x * blockDim.x + threadIdx.x;
    const int n = t >> 4;
    const int l = t & 15;
    if (n >= N_POINTS) return;
    float f0, f1;
    hash_point_level(x, tables, n, l, res.r[l], f0, f1);
    float2* o = reinterpret_cast<float2*>(out + (size_t)n * (NUM_LEVELS * LEVEL_DIM) + l * LEVEL_DIM);
    *o = make_float2(f0, f1);
}

extern "C" void kernel_launch(void* const* d_in, const int* in_sizes, int n_in,
                              void* d_out, int out_size, void* d_ws, size_t ws_size,
                              hipStream_t stream) {
    const float* x      = (const float*)d_in[0];
    const float* tables = (const float*)d_in[1];
    float* out          = (float*)d_out;

    ResArgs ra;
    const double b = exp((log(2048.0) - log(16.0)) / 15.0);
    for (int i = 0; i < NUM_LEVELS; ++i) {
        ra.r[i] = (float)floor(16.0 * pow(b, (double)i));
    }

    const size_t ws_needed = (size_t)NUM_LEVELS * N_POINTS * sizeof(float2); // 32 MB
    if (ws_size >= ws_needed) {
        float2* ws = (float2*)d_ws;
        hipLaunchKernelGGL(hash_embed_phase1, dim3(NUM_LEVELS * BLOCKS_PER_LEVEL), dim3(256),
                           0, stream, x, tables, ws, ra);
        hipLaunchKernelGGL(hash_embed_phase2, dim3(N_POINTS / 64), dim3(256),
                           0, stream, ws, (float2*)out);
    } else {
        const int total = N_POINTS * NUM_LEVELS;
        hipLaunchKernelGGL(hash_embed_direct, dim3((total + 255) / 256), dim3(256),
                           0, stream, x, tables, out, ra);
    }
}